// Round 20
// baseline (52.500 us; speedup 1.0000x reference)
//
#include <hip/hip_runtime.h>
#include <math.h>

#define N_NODES 50000
#define N_EDGES 800000
#define HIDDEN  256
#define OUT_DIM 10
#define LN_EPS  1e-5f

// hist slicing (packed-u16 LDS allows bigger partitions, more slices)
#define HES   64                   // hist edge slices
#define HNP   4                    // hist node partitions
#define HPART 12500                // nodes per hist partition
#define HEPSE (N_EDGES / HES)      // 12500 edges per slice
#define HEPSE4 (HEPSE / 4)         // 3125 int4 per slice

// scatter slicing (float LDS limits partition size)
#define NP    8                    // node partitions
#define PART  6250                 // nodes per partition
#define ES    32                   // edge slices
#define EPSE  (N_EDGES / ES)       // 25000 edges per slice
#define EPSE4 (EPSE / 4)           // 6250 int4 per slice

#define NH2   (N_NODES / 2)        // 25000 node pairs
#define NPB   128                  // nodes per ln block == chunk size
#define LNB   ((N_NODES + NPB - 1) / NPB)   // 391 blocks / chunks

// ---------------- D1: packed-u16 histogram (plain partial stores) ----------
// Block (slice s, part p): LDS histogram packed as u16 pairs (carry-safe:
// each half < 2^16). Per-block scan is 3125 int4 (half of round-16's 6250).
__global__ __launch_bounds__(1024) void hist_kernel(
    const int4* __restrict__ dst4, unsigned* __restrict__ degp32,
    float* __restrict__ pooled8,
    const float4* __restrict__ Wh4, const float4* __restrict__ Wo4)
{
    __shared__ unsigned hist[HPART / 2];     // 25 KB, u16 pairs
    const int tid = threadIdx.x;
    const int s = blockIdx.x, p = blockIdx.y;
    const int gb = p * HES + s;

    if (gb == 0) { pooled8[tid] = 0.f; pooled8[tid + 1024] = 0.f; }
    // L3-warm MLP weights for D4's single-block tail (keep-alive, no DCE)
    if (gb < 17) {
        const int idx = gb * 1024 + tid;
        if (idx < 16384) {
            const float4 v = Wh4[idx];
            asm volatile("" :: "v"(v.x + v.y + v.z + v.w));
        } else if (idx < 17024) {
            const float4 v = Wo4[idx - 16384];
            asm volatile("" :: "v"(v.x + v.y + v.z + v.w));
        }
    }

    for (int i = tid; i < HPART / 2; i += 1024) hist[i] = 0u;
    __syncthreads();

    const int base = p * HPART;
    const int b0 = s * HEPSE4;
    for (int i = tid; i < HEPSE4; i += 1024) {
        const int4 d = dst4[b0 + i];
        unsigned r;
        r = (unsigned)(d.x - base); if (r < HPART) atomicAdd(&hist[r >> 1], 1u << ((r & 1) * 16));
        r = (unsigned)(d.y - base); if (r < HPART) atomicAdd(&hist[r >> 1], 1u << ((r & 1) * 16));
        r = (unsigned)(d.z - base); if (r < HPART) atomicAdd(&hist[r >> 1], 1u << ((r & 1) * 16));
        r = (unsigned)(d.w - base); if (r < HPART) atomicAdd(&hist[r >> 1], 1u << ((r & 1) * 16));
    }
    __syncthreads();

    // LDS layout == store format (u16 pairs in node order): straight copy
    unsigned* outp = degp32 + (size_t)s * NH2 + base / 2;
    for (int i = tid; i < HPART / 2; i += 1024) outp[i] = hist[i];
}

// ---------------- D2: deg reduce (64 slices) -> dinv, y = dinv * x ---------
// Also zeroes the MLP ticket (boundary before D4 guarantees visibility).
__global__ __launch_bounds__(256) void dinv_y_kernel(
    const unsigned* __restrict__ degp32, const float4* __restrict__ nf4,
    float2* __restrict__ dinv2, float4* __restrict__ y4,
    unsigned* __restrict__ mlp_ticket)
{
    const int t = blockIdx.x * 256 + threadIdx.x;   // pair index
    if (t == 0) *mlp_ticket = 0u;
    if (t >= NH2) return;
    unsigned s0 = 0, s1 = 0;
    #pragma unroll
    for (int s = 0; s < HES; ++s) {
        const unsigned d = degp32[(size_t)s * NH2 + t];
        s0 += d & 0xFFFFu;
        s1 += d >> 16;
    }
    const float di0 = rsqrtf((float)s0 + 1.0f);
    const float di1 = rsqrtf((float)s1 + 1.0f);
    dinv2[t] = make_float2(di0, di1);
    const float4 x = nf4[t];
    y4[t] = make_float4(di0 * x.x, di0 * x.y, di1 * x.z, di1 * x.w);
}

// ---------------- D3: privatized scatter, chunk-transposed partials --------
// TpartB[chunk][slice][128 nodes]: flush coalesced (1KB runs, split only at
// partition edges), D4 reads ONE contiguous 32KB block per chunk.
__global__ __launch_bounds__(1024) void scatterp_kernel(
    const int4* __restrict__ src4, const int4* __restrict__ dst4,
    const float2* __restrict__ y, float2* __restrict__ TpartB2)
{
    __shared__ float Tl[2 * PART];           // 50 KB
    const int tid = threadIdx.x;
    const int s = blockIdx.x, p = blockIdx.y;

    for (int i = tid; i < 2 * PART; i += 1024) Tl[i] = 0.f;
    __syncthreads();

    const int base = p * PART;
    const int b0 = s * EPSE4;
    for (int i = tid; i < EPSE4; i += 1024) {
        const int4 d = dst4[b0 + i];
        const unsigned r0 = (unsigned)(d.x - base);
        const unsigned r1 = (unsigned)(d.y - base);
        const unsigned r2 = (unsigned)(d.z - base);
        const unsigned r3 = (unsigned)(d.w - base);
        if ((r0 < PART) | (r1 < PART) | (r2 < PART) | (r3 < PART)) {
            const int4 sv = src4[b0 + i];
            if (r0 < PART) { const float2 ys = y[sv.x]; atomicAdd(&Tl[2*r0], ys.x); atomicAdd(&Tl[2*r0+1], ys.y); }
            if (r1 < PART) { const float2 ys = y[sv.y]; atomicAdd(&Tl[2*r1], ys.x); atomicAdd(&Tl[2*r1+1], ys.y); }
            if (r2 < PART) { const float2 ys = y[sv.z]; atomicAdd(&Tl[2*r2], ys.x); atomicAdd(&Tl[2*r2+1], ys.y); }
            if (r3 < PART) { const float2 ys = y[sv.w]; atomicAdd(&Tl[2*r3], ys.x); atomicAdd(&Tl[2*r3+1], ys.y); }
        }
    }
    __syncthreads();

    const float2* Tl2 = (const float2*)Tl;
    for (int i = tid; i < PART; i += 1024) {
        const int n = base + i;
        const int idx = (((n >> 7) * ES + s) << 7) | (n & 127);
        TpartB2[idx] = Tl2[i];
    }
}

// ---- D4: chunk reduce + LN + pool + ticketed MLP tail (512 threads) -------
__global__ __launch_bounds__(512) void ln_pool_mlp_kernel(
    const float2* __restrict__ TpartB2,
    const float2* __restrict__ y,
    const float* __restrict__ dinv,
    const float* __restrict__ Wg, const float* __restrict__ bg,
    const float* __restrict__ gamma, const float* __restrict__ beta,
    const float* __restrict__ Wh, const float* __restrict__ bh,
    const float* __restrict__ Wo, const float* __restrict__ bo,
    float* __restrict__ pooled8,
    unsigned* __restrict__ ticket,
    float* __restrict__ out)
{
    const int tid  = threadIdx.x;
    const int bid  = blockIdx.x;
    const int n0   = bid * NPB;
    const int lane = tid & 63;
    const int wv   = tid >> 6;               // 8 waves

    __shared__ float4 nd[NPB];               // 2 KB (s0, s1, r, r*mu)
    __shared__ float  psx[8][NPB];           // 4 KB
    __shared__ float  psy[8][NPB];           // 4 KB
    __shared__ float  red[8][HIDDEN];        // 8 KB
    __shared__ float  pz[HIDDEN], zz[HIDDEN];
    __shared__ float  lgp[OUT_DIM][16], lg[OUT_DIM];
    __shared__ int    is_last;

    // chunk-local Tpart reduce: wave w sums slices 4w..4w+3 for both halves
    {
        const float2* tp = TpartB2 + (size_t)bid * (ES * NPB);
        float ax0 = 0.f, ay0 = 0.f, ax1 = 0.f, ay1 = 0.f;
        #pragma unroll
        for (int s4 = 0; s4 < 4; ++s4) {
            const int row = ((wv << 2) + s4) << 7;
            const float2 v0 = tp[row + lane];
            const float2 v1 = tp[row + 64 + lane];
            ax0 += v0.x; ay0 += v0.y;
            ax1 += v1.x; ay1 += v1.y;
        }
        psx[wv][lane] = ax0;      psy[wv][lane] = ay0;
        psx[wv][64 + lane] = ax1; psy[wv][64 + lane] = ay1;
    }
    __syncthreads();

    if (tid < NPB) {
        const int n = n0 + tid;
        float s0 = 0.f, s1 = 0.f;
        if (n < N_NODES) {
            float tx = 0.f, ty = 0.f;
            #pragma unroll
            for (int w = 0; w < 8; ++w) { tx += psx[w][tid]; ty += psy[w][tid]; }
            const float di = dinv[n];
            const float2 yn = y[n];
            s0 = di * (tx + yn.x);
            s1 = di * (ty + yn.y);
        }
        nd[tid] = make_float4(s0, s1, 0.f, 0.f);
    }
    __syncthreads();

    // pass 1: wave = (node-half h, col-group jg); W via scalar loads
    {
        const int wu  = __builtin_amdgcn_readfirstlane(wv);
        const int h   = wu & 1;
        const int jg  = wu >> 1;
        const float* w0p = Wg + jg * 64;
        const float* w1p = Wg + HIDDEN + jg * 64;
        const float* bgp = bg + jg * 64;
        const int node = h * 64 + lane;
        const float4 d = nd[node];
        float sumA = 0.f, sumB = 0.f, sqA = 0.f, sqB = 0.f;
        #pragma unroll 8
        for (int j = 0; j < 64; j += 2) {
            const float va = fmaxf(fmaf(d.y, w1p[j],     fmaf(d.x, w0p[j],     bgp[j])),     0.f);
            const float vb = fmaxf(fmaf(d.y, w1p[j + 1], fmaf(d.x, w0p[j + 1], bgp[j + 1])), 0.f);
            sumA += va; sqA = fmaf(va, va, sqA);
            sumB += vb; sqB = fmaf(vb, vb, sqB);
        }
        psx[jg][node] = sumA + sumB;   // reuse psx/psy as [4][128] sums
        psy[jg][node] = sqA + sqB;
    }
    __syncthreads();

    if (tid < NPB) {
        const float sum = psx[0][tid] + psx[1][tid] + psx[2][tid] + psx[3][tid];
        const float sq  = psy[0][tid] + psy[1][tid] + psy[2][tid] + psy[3][tid];
        const float mu  = sum * (1.0f / HIDDEN);
        const float var = sq * (1.0f / HIDDEN) - mu * mu;
        float r = rsqrtf(var + LN_EPS);
        if (n0 + tid >= N_NODES) r = 0.f;
        const float4 d = nd[tid];
        nd[tid] = make_float4(d.x, d.y, r, r * mu);
    }
    __syncthreads();

    // pass 2: wave = 16 nodes, lane = 4 columns
    {
        const float4 w0  = *reinterpret_cast<const float4*>(&Wg[lane * 4]);
        const float4 w1  = *reinterpret_cast<const float4*>(&Wg[HIDDEN + lane * 4]);
        const float4 bgv = *reinterpret_cast<const float4*>(&bg[lane * 4]);

        float a0 = 0.f, a1 = 0.f, a2 = 0.f, a3 = 0.f;
        #pragma unroll
        for (int k = 0; k < 16; ++k) {
            const float4 d = nd[wv * 16 + k];    // broadcast read
            const float v0 = fmaxf(fmaf(d.y, w1.x, fmaf(d.x, w0.x, bgv.x)), 0.f);
            const float v1 = fmaxf(fmaf(d.y, w1.y, fmaf(d.x, w0.y, bgv.y)), 0.f);
            const float v2 = fmaxf(fmaf(d.y, w1.z, fmaf(d.x, w0.z, bgv.z)), 0.f);
            const float v3 = fmaxf(fmaf(d.y, w1.w, fmaf(d.x, w0.w, bgv.w)), 0.f);
            a0 += fmaf(d.z, v0, -d.w);
            a1 += fmaf(d.z, v1, -d.w);
            a2 += fmaf(d.z, v2, -d.w);
            a3 += fmaf(d.z, v3, -d.w);
        }
        red[wv][lane * 4 + 0] = a0;
        red[wv][lane * 4 + 1] = a1;
        red[wv][lane * 4 + 2] = a2;
        red[wv][lane * 4 + 3] = a3;
    }
    __syncthreads();

    // pooled via atomics only (nothing bulk-dirty before the ticket)
    if (tid < HIDDEN) {
        float s = 0.f;
        #pragma unroll
        for (int w = 0; w < 8; ++w) s += red[w][tid];
        atomicAdd(&pooled8[(bid & 7) * HIDDEN + tid], s);
    }
    __syncthreads();

    if (tid == 0) {
        const unsigned old = __hip_atomic_fetch_add(ticket, 1u, __ATOMIC_ACQ_REL,
                                                    __HIP_MEMORY_SCOPE_AGENT);
        is_last = (old == (unsigned)(gridDim.x - 1));
    }
    __syncthreads();
    if (!is_last) return;

    if (tid < HIDDEN) {
        float S = 0.f;
        #pragma unroll
        for (int k = 0; k < 8; ++k) S += pooled8[k * HIDDEN + tid];
        pz[tid] = gamma[tid] * S + (float)N_NODES * beta[tid];
    }
    __syncthreads();

    // z = relu(bh + pooled @ Wh): 2-way k-split over 512 threads
    {
        const int g = tid >> 8;      // 0..1
        const int j = tid & 255;
        float acc = 0.f;
        #pragma unroll 8
        for (int k = g * 128; k < g * 128 + 128; ++k)
            acc = fmaf(pz[k], Wh[k * HIDDEN + j], acc);
        red[g][j] = acc;
    }
    __syncthreads();
    if (tid < HIDDEN)
        zz[tid] = fmaxf(bh[tid] + red[0][tid] + red[1][tid], 0.f);
    __syncthreads();

    // logits: 16 threads per output, 16 k's each
    if (tid < OUT_DIM * 16) {
        const int o = tid >> 4, kc = tid & 15;
        float acc = 0.f;
        #pragma unroll
        for (int k = kc * 16; k < kc * 16 + 16; ++k)
            acc = fmaf(zz[k], Wo[k * OUT_DIM + o], acc);
        lgp[o][kc] = acc;
    }
    __syncthreads();
    if (tid < OUT_DIM) {
        float t = bo[tid];
        #pragma unroll
        for (int q = 0; q < 16; ++q) t += lgp[tid][q];
        lg[tid] = t;
    }
    __syncthreads();

    if (tid == 0) {
        float m = lg[0];
        for (int k = 1; k < OUT_DIM; ++k) m = fmaxf(m, lg[k]);
        float sum = 0.f;
        for (int k = 0; k < OUT_DIM; ++k) sum += expf(lg[k] - m);
        const float lse = m + logf(sum);
        for (int k = 0; k < OUT_DIM; ++k) out[k] = lg[k] - lse;
    }
}

// ---------------------------------------------------------------- launch ----
extern "C" void kernel_launch(void* const* d_in, const int* in_sizes, int n_in,
                              void* d_out, int out_size, void* d_ws, size_t ws_size,
                              hipStream_t stream) {
    const float* nf    = (const float*)d_in[0];   // [N, 2]
    const int*   ei    = (const int*)  d_in[1];   // [2, E] int32
    const float* Wg    = (const float*)d_in[2];
    const float* bg    = (const float*)d_in[3];
    const float* gamma = (const float*)d_in[4];
    const float* beta  = (const float*)d_in[5];
    const float* Wh    = (const float*)d_in[6];
    const float* bh    = (const float*)d_in[7];
    const float* Wo    = (const float*)d_in[8];
    const float* bo    = (const float*)d_in[9];
    float* out = (float*)d_out;

    const int* srcp = ei;
    const int* dstp = ei + N_EDGES;               // 3.2MB offset: 16B-aligned

    // workspace layout (4B units):
    // pooled8 [8*H] | mlp_ticket [16] | degp32 [HES*NH2] (6.4MB)
    // | TpartB [LNB*ES*128] float2 (12.8MB) | dinv [N] | y [2N]
    float* pooled8 = (float*)d_ws;
    unsigned* mlp_ticket = (unsigned*)(pooled8 + 8 * HIDDEN);
    unsigned* degp32 = mlp_ticket + 16;
    float* TpartB = (float*)(degp32 + (size_t)HES * NH2);
    float* dinvp  = TpartB + (size_t)LNB * ES * NPB * 2;
    float* yp     = dinvp + N_NODES;

    dim3 hg(HES, HNP);
    dim3 pg(ES, NP);
    hist_kernel<<<hg, 1024, 0, stream>>>((const int4*)dstp, degp32, pooled8,
                                         (const float4*)Wh, (const float4*)Wo);
    dinv_y_kernel<<<(NH2 + 255) / 256, 256, 0, stream>>>(degp32, (const float4*)nf,
                                                         (float2*)dinvp, (float4*)yp,
                                                         mlp_ticket);
    scatterp_kernel<<<pg, 1024, 0, stream>>>((const int4*)srcp, (const int4*)dstp,
                                             (const float2*)yp, (float2*)TpartB);
    ln_pool_mlp_kernel<<<LNB, 512, 0, stream>>>((const float2*)TpartB,
                                                (const float2*)yp, dinvp,
                                                Wg, bg, gamma, beta, Wh, bh, Wo, bo,
                                                pooled8, mlp_ticket, out);
}

// Round 21
// 51.545 us; speedup vs baseline: 1.0185x; 1.0185x over previous
//
#include <hip/hip_runtime.h>
#include <math.h>

#define N_NODES 50000
#define N_EDGES 800000
#define HIDDEN  256
#define OUT_DIM 10
#define LN_EPS  1e-5f

#define NP    8                    // node partitions
#define PART  6250                 // nodes per partition
#define ES    32                   // edge slices
#define EPSE  (N_EDGES / ES)       // 25000 edges per slice
#define EPSE4 (EPSE / 4)           // 6250 int4 per slice
#define NH2   (N_NODES / 2)        // 25000 node pairs
#define NPB   128                  // nodes per ln block == chunk size
#define LNB   ((N_NODES + NPB - 1) / NPB)   // 391 blocks / chunks

// ---------------- D1: privatized histogram (plain partial stores) ----------
__global__ __launch_bounds__(1024) void hist_kernel(
    const int4* __restrict__ dst4, unsigned* __restrict__ degp32,
    float* __restrict__ pooled8,
    const float4* __restrict__ Wh4, const float4* __restrict__ Wo4)
{
    __shared__ unsigned hist[PART];          // 25 KB
    const int tid = threadIdx.x;
    const int s = blockIdx.x, p = blockIdx.y;
    const int gb = p * ES + s;

    if (gb == 0) { pooled8[tid] = 0.f; pooled8[tid + 1024] = 0.f; }
    // L3-warm MLP weights for D4's single-block tail (keep-alive, no DCE)
    if (gb < 17) {
        const int idx = gb * 1024 + tid;
        if (idx < 16384) {
            const float4 v = Wh4[idx];
            asm volatile("" :: "v"(v.x + v.y + v.z + v.w));
        } else if (idx < 17024) {
            const float4 v = Wo4[idx - 16384];
            asm volatile("" :: "v"(v.x + v.y + v.z + v.w));
        }
    }

    for (int i = tid; i < PART; i += 1024) hist[i] = 0u;
    __syncthreads();

    const int base = p * PART;
    const int b0 = s * EPSE4;
    for (int i = tid; i < EPSE4; i += 1024) {
        const int4 d = dst4[b0 + i];
        unsigned r;
        r = (unsigned)(d.x - base); if (r < PART) atomicAdd(&hist[r], 1u);
        r = (unsigned)(d.y - base); if (r < PART) atomicAdd(&hist[r], 1u);
        r = (unsigned)(d.z - base); if (r < PART) atomicAdd(&hist[r], 1u);
        r = (unsigned)(d.w - base); if (r < PART) atomicAdd(&hist[r], 1u);
    }
    __syncthreads();

    unsigned* outp = degp32 + (size_t)s * NH2 + base / 2;
    for (int i = tid; i < PART / 2; i += 1024)
        outp[i] = (hist[2 * i] & 0xFFFFu) | (hist[2 * i + 1] << 16);
}

// ---------------- D2: deg reduce -> dinv, y = dinv * x ---------------------
// Also zeroes the MLP ticket (boundary before D4 guarantees visibility).
__global__ __launch_bounds__(256) void dinv_y_kernel(
    const unsigned* __restrict__ degp32, const float4* __restrict__ nf4,
    float2* __restrict__ dinv2, float4* __restrict__ y4,
    unsigned* __restrict__ mlp_ticket)
{
    const int t = blockIdx.x * 256 + threadIdx.x;   // pair index
    if (t == 0) *mlp_ticket = 0u;
    if (t >= NH2) return;
    unsigned s0 = 0, s1 = 0;
    #pragma unroll
    for (int s = 0; s < ES; ++s) {
        const unsigned d = degp32[(size_t)s * NH2 + t];
        s0 += d & 0xFFFFu;
        s1 += d >> 16;
    }
    const float di0 = rsqrtf((float)s0 + 1.0f);
    const float di1 = rsqrtf((float)s1 + 1.0f);
    dinv2[t] = make_float2(di0, di1);
    const float4 x = nf4[t];
    y4[t] = make_float4(di0 * x.x, di0 * x.y, di1 * x.z, di1 * x.w);
}

// ---------------- D3: privatized scatter, chunk-transposed partials --------
// TpartB[chunk][slice][128 nodes]: flush coalesced (1KB runs, split only at
// partition edges), D4 reads ONE contiguous 32KB block per chunk.
__global__ __launch_bounds__(1024) void scatterp_kernel(
    const int4* __restrict__ src4, const int4* __restrict__ dst4,
    const float2* __restrict__ y, float2* __restrict__ TpartB2)
{
    __shared__ float Tl[2 * PART];           // 50 KB
    const int tid = threadIdx.x;
    const int s = blockIdx.x, p = blockIdx.y;

    for (int i = tid; i < 2 * PART; i += 1024) Tl[i] = 0.f;
    __syncthreads();

    const int base = p * PART;
    const int b0 = s * EPSE4;
    for (int i = tid; i < EPSE4; i += 1024) {
        const int4 d = dst4[b0 + i];
        const unsigned r0 = (unsigned)(d.x - base);
        const unsigned r1 = (unsigned)(d.y - base);
        const unsigned r2 = (unsigned)(d.z - base);
        const unsigned r3 = (unsigned)(d.w - base);
        if ((r0 < PART) | (r1 < PART) | (r2 < PART) | (r3 < PART)) {
            const int4 sv = src4[b0 + i];
            if (r0 < PART) { const float2 ys = y[sv.x]; atomicAdd(&Tl[2*r0], ys.x); atomicAdd(&Tl[2*r0+1], ys.y); }
            if (r1 < PART) { const float2 ys = y[sv.y]; atomicAdd(&Tl[2*r1], ys.x); atomicAdd(&Tl[2*r1+1], ys.y); }
            if (r2 < PART) { const float2 ys = y[sv.z]; atomicAdd(&Tl[2*r2], ys.x); atomicAdd(&Tl[2*r2+1], ys.y); }
            if (r3 < PART) { const float2 ys = y[sv.w]; atomicAdd(&Tl[2*r3], ys.x); atomicAdd(&Tl[2*r3+1], ys.y); }
        }
    }
    __syncthreads();

    const float2* Tl2 = (const float2*)Tl;
    for (int i = tid; i < PART; i += 1024) {
        const int n = base + i;
        const int idx = (((n >> 7) * ES + s) << 7) | (n & 127);
        TpartB2[idx] = Tl2[i];
    }
}

// ---- D4: chunk reduce + LN + pool + ticketed MLP tail (512 threads) -------
// Block bid == chunk bid (128 nodes). 8 waves: chunk reduce 4 slices/wave;
// pass1 = 4 col-groups x 2 node-halves (no cross-lane ops); pass2 = 8 waves
// x 16 nodes. Ticket-after-atomics only.
__global__ __launch_bounds__(512) void ln_pool_mlp_kernel(
    const float2* __restrict__ TpartB2,
    const float2* __restrict__ y,
    const float* __restrict__ dinv,
    const float* __restrict__ Wg, const float* __restrict__ bg,
    const float* __restrict__ gamma, const float* __restrict__ beta,
    const float* __restrict__ Wh, const float* __restrict__ bh,
    const float* __restrict__ Wo, const float* __restrict__ bo,
    float* __restrict__ pooled8,
    unsigned* __restrict__ ticket,
    float* __restrict__ out)
{
    const int tid  = threadIdx.x;
    const int bid  = blockIdx.x;
    const int n0   = bid * NPB;
    const int lane = tid & 63;
    const int wv   = tid >> 6;               // 8 waves

    __shared__ float4 nd[NPB];               // 2 KB (s0, s1, r, r*mu)
    __shared__ float  psx[8][NPB];           // 4 KB
    __shared__ float  psy[8][NPB];           // 4 KB
    __shared__ float  red[8][HIDDEN];        // 8 KB
    __shared__ float  pz[HIDDEN], zz[HIDDEN];
    __shared__ float  lgp[OUT_DIM][16], lg[OUT_DIM];
    __shared__ int    is_last;

    // chunk-local Tpart reduce: wave w sums slices 4w..4w+3 for both
    // node-halves (contiguous 1KB rows).
    {
        const float2* tp = TpartB2 + (size_t)bid * (ES * NPB);
        float ax0 = 0.f, ay0 = 0.f, ax1 = 0.f, ay1 = 0.f;
        #pragma unroll
        for (int s4 = 0; s4 < 4; ++s4) {
            const int row = ((wv << 2) + s4) << 7;
            const float2 v0 = tp[row + lane];
            const float2 v1 = tp[row + 64 + lane];
            ax0 += v0.x; ay0 += v0.y;
            ax1 += v1.x; ay1 += v1.y;
        }
        psx[wv][lane] = ax0;      psy[wv][lane] = ay0;
        psx[wv][64 + lane] = ax1; psy[wv][64 + lane] = ay1;
    }
    __syncthreads();

    if (tid < NPB) {
        const int n = n0 + tid;
        float s0 = 0.f, s1 = 0.f;
        if (n < N_NODES) {
            float tx = 0.f, ty = 0.f;
            #pragma unroll
            for (int w = 0; w < 8; ++w) { tx += psx[w][tid]; ty += psy[w][tid]; }
            const float di = dinv[n];
            const float2 yn = y[n];
            s0 = di * (tx + yn.x);
            s1 = di * (ty + yn.y);
        }
        nd[tid] = make_float4(s0, s1, 0.f, 0.f);
    }
    __syncthreads();

    // pass 1: wave = (node-half h, col-group jg); lane = node within half.
    // W via wave-uniform scalar loads; no cross-lane ops.
    {
        const int wu  = __builtin_amdgcn_readfirstlane(wv);
        const int h   = wu & 1;
        const int jg  = wu >> 1;
        const float* w0p = Wg + jg * 64;
        const float* w1p = Wg + HIDDEN + jg * 64;
        const float* bgp = bg + jg * 64;
        const int node = h * 64 + lane;
        const float4 d = nd[node];
        float sumA = 0.f, sumB = 0.f, sqA = 0.f, sqB = 0.f;
        #pragma unroll 8
        for (int j = 0; j < 64; j += 2) {
            const float va = fmaxf(fmaf(d.y, w1p[j],     fmaf(d.x, w0p[j],     bgp[j])),     0.f);
            const float vb = fmaxf(fmaf(d.y, w1p[j + 1], fmaf(d.x, w0p[j + 1], bgp[j + 1])), 0.f);
            sumA += va; sqA = fmaf(va, va, sqA);
            sumB += vb; sqB = fmaf(vb, vb, sqB);
        }
        psx[jg][node] = sumA + sumB;   // reuse psx/psy as [4][128] sums
        psy[jg][node] = sqA + sqB;
    }
    __syncthreads();

    if (tid < NPB) {
        const float sum = psx[0][tid] + psx[1][tid] + psx[2][tid] + psx[3][tid];
        const float sq  = psy[0][tid] + psy[1][tid] + psy[2][tid] + psy[3][tid];
        const float mu  = sum * (1.0f / HIDDEN);
        const float var = sq * (1.0f / HIDDEN) - mu * mu;
        float r = rsqrtf(var + LN_EPS);
        if (n0 + tid >= N_NODES) r = 0.f;
        const float4 d = nd[tid];
        nd[tid] = make_float4(d.x, d.y, r, r * mu);
    }
    __syncthreads();

    // pass 2: wave = 16 nodes, lane = 4 columns
    {
        const float4 w0  = *reinterpret_cast<const float4*>(&Wg[lane * 4]);
        const float4 w1  = *reinterpret_cast<const float4*>(&Wg[HIDDEN + lane * 4]);
        const float4 bgv = *reinterpret_cast<const float4*>(&bg[lane * 4]);

        float a0 = 0.f, a1 = 0.f, a2 = 0.f, a3 = 0.f;
        #pragma unroll
        for (int k = 0; k < 16; ++k) {
            const float4 d = nd[wv * 16 + k];    // broadcast read
            const float v0 = fmaxf(fmaf(d.y, w1.x, fmaf(d.x, w0.x, bgv.x)), 0.f);
            const float v1 = fmaxf(fmaf(d.y, w1.y, fmaf(d.x, w0.y, bgv.y)), 0.f);
            const float v2 = fmaxf(fmaf(d.y, w1.z, fmaf(d.x, w0.z, bgv.z)), 0.f);
            const float v3 = fmaxf(fmaf(d.y, w1.w, fmaf(d.x, w0.w, bgv.w)), 0.f);
            a0 += fmaf(d.z, v0, -d.w);
            a1 += fmaf(d.z, v1, -d.w);
            a2 += fmaf(d.z, v2, -d.w);
            a3 += fmaf(d.z, v3, -d.w);
        }
        red[wv][lane * 4 + 0] = a0;
        red[wv][lane * 4 + 1] = a1;
        red[wv][lane * 4 + 2] = a2;
        red[wv][lane * 4 + 3] = a3;
    }
    __syncthreads();

    // pooled via atomics only (nothing bulk-dirty before the ticket)
    if (tid < HIDDEN) {
        float s = 0.f;
        #pragma unroll
        for (int w = 0; w < 8; ++w) s += red[w][tid];
        atomicAdd(&pooled8[(bid & 7) * HIDDEN + tid], s);
    }
    __syncthreads();

    if (tid == 0) {
        const unsigned old = __hip_atomic_fetch_add(ticket, 1u, __ATOMIC_ACQ_REL,
                                                    __HIP_MEMORY_SCOPE_AGENT);
        is_last = (old == (unsigned)(gridDim.x - 1));
    }
    __syncthreads();
    if (!is_last) return;

    if (tid < HIDDEN) {
        float S = 0.f;
        #pragma unroll
        for (int k = 0; k < 8; ++k) S += pooled8[k * HIDDEN + tid];
        pz[tid] = gamma[tid] * S + (float)N_NODES * beta[tid];
    }
    __syncthreads();

    // z = relu(bh + pooled @ Wh): 2-way k-split over 512 threads
    {
        const int g = tid >> 8;      // 0..1
        const int j = tid & 255;
        float acc = 0.f;
        #pragma unroll 8
        for (int k = g * 128; k < g * 128 + 128; ++k)
            acc = fmaf(pz[k], Wh[k * HIDDEN + j], acc);
        red[g][j] = acc;
    }
    __syncthreads();
    if (tid < HIDDEN)
        zz[tid] = fmaxf(bh[tid] + red[0][tid] + red[1][tid], 0.f);
    __syncthreads();

    // logits: 16 threads per output, 16 k's each
    if (tid < OUT_DIM * 16) {
        const int o = tid >> 4, kc = tid & 15;
        float acc = 0.f;
        #pragma unroll
        for (int k = kc * 16; k < kc * 16 + 16; ++k)
            acc = fmaf(zz[k], Wo[k * OUT_DIM + o], acc);
        lgp[o][kc] = acc;
    }
    __syncthreads();
    if (tid < OUT_DIM) {
        float t = bo[tid];
        #pragma unroll
        for (int q = 0; q < 16; ++q) t += lgp[tid][q];
        lg[tid] = t;
    }
    __syncthreads();

    if (tid == 0) {
        float m = lg[0];
        for (int k = 1; k < OUT_DIM; ++k) m = fmaxf(m, lg[k]);
        float sum = 0.f;
        for (int k = 0; k < OUT_DIM; ++k) sum += expf(lg[k] - m);
        const float lse = m + logf(sum);
        for (int k = 0; k < OUT_DIM; ++k) out[k] = lg[k] - lse;
    }
}

// ---------------------------------------------------------------- launch ----
extern "C" void kernel_launch(void* const* d_in, const int* in_sizes, int n_in,
                              void* d_out, int out_size, void* d_ws, size_t ws_size,
                              hipStream_t stream) {
    const float* nf    = (const float*)d_in[0];   // [N, 2]
    const int*   ei    = (const int*)  d_in[1];   // [2, E] int32
    const float* Wg    = (const float*)d_in[2];
    const float* bg    = (const float*)d_in[3];
    const float* gamma = (const float*)d_in[4];
    const float* beta  = (const float*)d_in[5];
    const float* Wh    = (const float*)d_in[6];
    const float* bh    = (const float*)d_in[7];
    const float* Wo    = (const float*)d_in[8];
    const float* bo    = (const float*)d_in[9];
    float* out = (float*)d_out;

    const int* srcp = ei;
    const int* dstp = ei + N_EDGES;               // 3.2MB offset: 16B-aligned

    // workspace layout (4B units):
    // pooled8 [8*H] | mlp_ticket [16] | degp32 [ES*NH2] (3.2MB)
    // | TpartB [LNB*ES*128] float2 (12.8MB) | dinv [N] | y [2N]
    float* pooled8 = (float*)d_ws;
    unsigned* mlp_ticket = (unsigned*)(pooled8 + 8 * HIDDEN);
    unsigned* degp32 = mlp_ticket + 16;
    float* TpartB = (float*)(degp32 + (size_t)ES * NH2);
    float* dinvp  = TpartB + (size_t)LNB * ES * NPB * 2;
    float* yp     = dinvp + N_NODES;

    dim3 pg(ES, NP);
    hist_kernel<<<pg, 1024, 0, stream>>>((const int4*)dstp, degp32, pooled8,
                                         (const float4*)Wh, (const float4*)Wo);
    dinv_y_kernel<<<(NH2 + 255) / 256, 256, 0, stream>>>(degp32, (const float4*)nf,
                                                         (float2*)dinvp, (float4*)yp,
                                                         mlp_ticket);
    scatterp_kernel<<<pg, 1024, 0, stream>>>((const int4*)srcp, (const int4*)dstp,
                                             (const float2*)yp, (float2*)TpartB);
    ln_pool_mlp_kernel<<<LNB, 512, 0, stream>>>((const float2*)TpartB,
                                                (const float2*)yp, dinvp,
                                                Wg, bg, gamma, beta, Wh, bh, Wo, bo,
                                                pooled8, mlp_ticket, out);
}